// Round 11
// baseline (319.983 us; speedup 1.0000x reference)
//
#include <hip/hip_runtime.h>
#include <hip/hip_bf16.h>
#include <math.h>

typedef short short8 __attribute__((ext_vector_type(8)));
typedef float f32x4  __attribute__((ext_vector_type(4)));
typedef unsigned int u32;

#define B_ROWS 8192
#define IN_DIM 1024
#define OUT_DIM 256
#define M_DIM 1280
#define P_DIM 2304
#define NJ 10
#define RB 16                  // rows per block -> 512 blocks, 2 blocks/CU
#define BK 64
#define HG_COLS 1152

// ws: Xbf bf16[8192][1024] ; Wbf bf16[1280][2304] ; Hg bf16[8192][1152]
#define WBF_OFF (B_ROWS * (size_t)IN_DIM * 2)
#define HG_OFF  (WBF_OFF + (size_t)M_DIM * P_DIM * 2)

__device__ __forceinline__ short f2bf(float x)
{
    __hip_bfloat16 h = __float2bfloat16(x);
    return *(short*)&h;
}

__device__ __forceinline__ float tanh_fast(float x)
{
    x = fminf(fmaxf(x, -15.f), 15.f);
    float e = __expf(2.f * x);
    return (e - 1.f) * __builtin_amdgcn_rcpf(e + 1.f);
}

__global__ __launch_bounds__(256)
void convert_x(const float* __restrict__ x, short* __restrict__ Xbf)
{
    int idx = blockIdx.x * 256 + threadIdx.x;
    int r  = idx >> 7;
    int c8 = (idx & 127) << 3;
    const float* src = x + (size_t)r * IN_DIM + c8;
    float4 a0 = *(const float4*)src;
    float4 a1 = *(const float4*)(src + 4);
    short8 s;
    s[0] = f2bf(a0.x); s[1] = f2bf(a0.y); s[2] = f2bf(a0.z); s[3] = f2bf(a0.w);
    s[4] = f2bf(a1.x); s[5] = f2bf(a1.y); s[6] = f2bf(a1.z); s[7] = f2bf(a1.w);
    *(short8*)(Xbf + (size_t)r * IN_DIM + c8) = s;
}

__global__ __launch_bounds__(256)
void convert_w(const float* __restrict__ W, short* __restrict__ Wbf)
{
    size_t e8 = ((size_t)blockIdx.x * 256 + threadIdx.x) * 8;
    float4 a0 = *(const float4*)(W + e8);
    float4 a1 = *(const float4*)(W + e8 + 4);
    short8 s;
    s[0] = f2bf(a0.x); s[1] = f2bf(a0.y); s[2] = f2bf(a0.z); s[3] = f2bf(a0.w);
    s[4] = f2bf(a1.x); s[5] = f2bf(a1.y); s[6] = f2bf(a1.z); s[7] = f2bf(a1.w);
    *(short8*)(Wbf + e8) = s;
}

// LDS union (76,032 B):
//  GEMM: xs[2] @0/@2048 ; Wst[2] @4096/@20480 (ends 36,864)  [XOR-swizzled]
//  seq : PreL f32[16][132] @0 (8,448) ; lwf f32[128][132] @8448 (67,584)
#define LWF_OFF 8448
#define PLS 132
#define LWS 132

__global__ __launch_bounds__(256, 2)
void fused(const short* __restrict__ Xbf, const short* __restrict__ Wbf,
           const float* __restrict__ Wf, short* __restrict__ Hg,
           const float* __restrict__ bias, float* __restrict__ out)
{
    __shared__ __align__(16) char L[76032];

    const int tid  = threadIdx.x;
    const int lane = tid & 63;
    const int w    = tid >> 6;
    const int fr   = lane & 15;
    const int fq   = lane >> 4;
    const int r4   = lane & 3;      // seq: row within wave's 4
    const int sl   = lane >> 2;     // seq: slice 0..15 (8 u's)
    const int srow = w * 4 + r4;
    const int bm   = blockIdx.x * RB;
    const int sa_r  = tid >> 3;
    const int sa_k8 = (tid & 7) << 3;

#pragma unroll 1
    for (int J = 0; J < NJ; ++J) {
        const int j0 = J * 128;
        const int nt = (IN_DIM + j0) / BK;

        f32x4 acc0 = {0.f, 0.f, 0.f, 0.f};
        f32x4 acc1 = {0.f, 0.f, 0.f, 0.f};

        __syncthreads();   // prev J fully done (lwf/PreL free)

        short8 ra; short8 rw[4];
        {
            if (tid < 128)
                ra = *(const short8*)(Xbf + (size_t)(bm + sa_r) * IN_DIM + sa_k8);
#pragma unroll
            for (int c = 0; c < 4; ++c) {
                int idx = tid + c * 256;
                int n = idx >> 3, k8 = (idx & 7) << 3;
                rw[c] = *(const short8*)(Wbf + (size_t)(j0 + n) * P_DIM + k8);
            }
            if (tid < 128)
                *(short8*)(L + ((sa_r * 128 + sa_k8 * 2) ^ ((sa_r & 7) << 4))) = ra;
#pragma unroll
            for (int c = 0; c < 4; ++c) {
                int idx = tid + c * 256;
                int n = idx >> 3, k8 = (idx & 7) << 3;
                *(short8*)(L + 4096 + ((n * 128 + k8 * 2) ^ ((n & 7) << 4))) = rw[c];
            }
        }

#pragma unroll 1
        for (int t = 0; t < nt; ++t) {
            if (t + 1 < nt) {
                int k0 = (t + 1) * BK;
                if (tid < 128) {
                    const short* src = (k0 < IN_DIM)
                        ? (Xbf + (size_t)(bm + sa_r) * IN_DIM + k0 + sa_k8)
                        : (Hg + (size_t)(bm + sa_r) * HG_COLS + (k0 - IN_DIM) + sa_k8);
                    ra = *(const short8*)src;
                }
#pragma unroll
                for (int c = 0; c < 4; ++c) {
                    int idx = tid + c * 256;
                    int n = idx >> 3, k8 = (idx & 7) << 3;
                    rw[c] = *(const short8*)(Wbf + (size_t)(j0 + n) * P_DIM + k0 + k8);
                }
            }
            __syncthreads();
            const char* xb = L + (t & 1) * 2048;
            const char* wb = L + 4096 + (t & 1) * 16384;
            const int n0 = w * 32 + fr;
            const int n1 = n0 + 16;
#pragma unroll
            for (int k32 = 0; k32 < 2; ++k32) {
                int kb = k32 * 64 + fq * 16;
                short8 a  = *(const short8*)(xb + ((fr * 128 + kb) ^ ((fr & 7) << 4)));
                short8 b0 = *(const short8*)(wb + ((n0 * 128 + kb) ^ ((n0 & 7) << 4)));
                short8 b1 = *(const short8*)(wb + ((n1 * 128 + kb) ^ ((n1 & 7) << 4)));
                acc0 = __builtin_amdgcn_mfma_f32_16x16x32_bf16(a, b0, acc0, 0, 0, 0);
                acc1 = __builtin_amdgcn_mfma_f32_16x16x32_bf16(a, b1, acc1, 0, 0, 0);
            }
            if (t + 1 < nt) {
                char* xw = L + ((t + 1) & 1) * 2048;
                char* ww = L + 4096 + ((t + 1) & 1) * 16384;
                if (tid < 128)
                    *(short8*)(xw + ((sa_r * 128 + sa_k8 * 2) ^ ((sa_r & 7) << 4))) = ra;
#pragma unroll
                for (int c = 0; c < 4; ++c) {
                    int idx = tid + c * 256;
                    int n = idx >> 3, k8 = (idx & 7) << 3;
                    *(short8*)(ww + ((n * 128 + k8 * 2) ^ ((n & 7) << 4))) = rw[c];
                }
            }
        }
        __syncthreads();   // MFMAs done; LDS free for seq overlay

        // ---- epilogue: PreL = acc + bias; stage lwf f32 (tri-zeroed) ------
        {
            float* PreL = (float*)L;
            float bv0 = bias[j0 + w * 32 + fr];
            float bv1 = bias[j0 + w * 32 + 16 + fr];
#pragma unroll
            for (int r = 0; r < 4; ++r) {
                PreL[(fq * 4 + r) * PLS + w * 32 + fr]      = acc0[r] + bv0;
                PreL[(fq * 4 + r) * PLS + w * 32 + 16 + fr] = acc1[r] + bv1;
            }
            float* lwf = (float*)(L + LWF_OFF);
            int u = tid & 127, th = tid >> 7;
#pragma unroll
            for (int it = 0; it < 16; ++it) {
                int t4 = (it * 2 + th) * 4;
                float4 v = *(const float4*)(Wf + (size_t)(j0 + u) * P_DIM + IN_DIM + j0 + t4);
                lwf[(t4 + 0) * LWS + u] = (u > t4 + 0) ? v.x : 0.f;
                lwf[(t4 + 1) * LWS + u] = (u > t4 + 1) ? v.y : 0.f;
                lwf[(t4 + 2) * LWS + u] = (u > t4 + 2) ? v.z : 0.f;
                lwf[(t4 + 3) * LWS + u] = (u > t4 + 3) ? v.w : 0.f;
            }
        }
        __syncthreads();

        float as[8];
        {
            const float* pr = (const float*)L + srow * PLS + sl * 8;
            f32x4 v0 = *(const f32x4*)pr;
            f32x4 v1 = *(const f32x4*)(pr + 4);
            as[0] = v0[0]; as[1] = v0[1]; as[2] = v0[2]; as[3] = v0[3];
            as[4] = v1[0]; as[5] = v1[1]; as[6] = v1[2]; as[7] = v1[3];
        }

        // ---- seq: 16 groups of 8 neurons; micro-triangle + bpermute burst -
        const float* lwf = (const float*)(L + LWF_OFF);
#pragma unroll 1
        for (int g = 0; g < 16; ++g) {
            const int  hsrc = r4 | (g << 2);
            const bool own  = (sl == g);

            // burst-prefetch this group's 16 weight quads (one DS latency)
            f32x4 wq[16];
#pragma unroll
            for (int s = 0; s < 8; ++s) {
                const float* wr_ = lwf + (g * 8 + s) * LWS + sl * 8;
                wq[2 * s]     = *(const f32x4*)wr_;
                wq[2 * s + 1] = *(const f32x4*)(wr_ + 4);
            }

            // 8x8 micro-triangle on private regs (valid only for owner lane)
            float tt[8], hh[8];
#pragma unroll
            for (int e = 0; e < 8; ++e) tt[e] = as[e];
#pragma unroll
            for (int s = 0; s < 8; ++s) {
                hh[s] = tanh_fast(tt[s]);
#pragma unroll
                for (int e = s + 1; e < 8; ++e) {
                    float wv = (e < 4) ? wq[2 * s][e] : wq[2 * s + 1][e - 4];
                    tt[e] += wv * hh[s];
                }
            }

            // broadcast the owner's 8 h values (one burst)
            float hb[8];
#pragma unroll
            for (int s = 0; s < 8; ++s) hb[s] = __shfl(hh[s], hsrc);

            // apply rank-8 update (tri-zeros make past slices no-ops)
#pragma unroll
            for (int e = 0; e < 8; ++e) {
                float v = as[e];
#pragma unroll
                for (int s = 0; s < 8; ++s) {
                    float wv = (e < 4) ? wq[2 * s][e] : wq[2 * s + 1][e - 4];
                    v += wv * hb[s];
                }
                as[e] = own ? hb[e] : v;
            }
        }

        // ---- write h to global H panel / output ---------------------------
        if (J < 9) {
            short8 hv;
#pragma unroll
            for (int e = 0; e < 8; ++e) hv[e] = f2bf(as[e]);
            *(short8*)(Hg + (size_t)(bm + srow) * HG_COLS + j0 + sl * 8) = hv;
        }
        if (J >= 8) {
            float* op = out + (size_t)(bm + srow) * OUT_DIM + (j0 - IN_DIM) + sl * 8;
            float4 o0, o1;
            o0.x = 1.f / (1.f + __expf(-as[0]));
            o0.y = 1.f / (1.f + __expf(-as[1]));
            o0.z = 1.f / (1.f + __expf(-as[2]));
            o0.w = 1.f / (1.f + __expf(-as[3]));
            o1.x = 1.f / (1.f + __expf(-as[4]));
            o1.y = 1.f / (1.f + __expf(-as[5]));
            o1.z = 1.f / (1.f + __expf(-as[6]));
            o1.w = 1.f / (1.f + __expf(-as[7]));
            *(float4*)op = o0;
            *(float4*)(op + 4) = o1;
        }
    }
}

extern "C" void kernel_launch(void* const* d_in, const int* in_sizes, int n_in,
                              void* d_out, int out_size, void* d_ws, size_t ws_size,
                              hipStream_t stream)
{
    const float* x    = (const float*)d_in[0];
    const float* W    = (const float*)d_in[1];
    const float* bias = (const float*)d_in[2];
    float* out = (float*)d_out;
    short* Xbf = (short*)d_ws;
    short* Wbf = (short*)((char*)d_ws + WBF_OFF);
    short* Hg  = (short*)((char*)d_ws + HG_OFF);

    convert_x<<<dim3(B_ROWS * IN_DIM / 8 / 256), dim3(256), 0, stream>>>(x, Xbf);
    convert_w<<<dim3(M_DIM * P_DIM / 8 / 256), dim3(256), 0, stream>>>(W, Wbf);
    fused<<<dim3(B_ROWS / RB), dim3(256), 0, stream>>>(Xbf, Wbf, W, Hg, bias, out);
}